// Round 5
// baseline (7842.987 us; speedup 1.0000x reference)
//
#include <hip/hip_runtime.h>
#include <hip/hip_bf16.h>

#define BATCH   2
#define SEQ     4096
#define DMODEL  512
#define DINNER  1024
#define DSTATE  64
#define NHEADS  16
#define HEADDIM 64
#define CONVDIM 1152
#define NPROJ   2192
#define MROWS   (BATCH*SEQ)   // 8192
#define QCH     64
#define NCHUNK  (SEQ/QCH)     // 64 chunks per batch

typedef short bf16x8 __attribute__((ext_vector_type(8)));
typedef float f32x4  __attribute__((ext_vector_type(4)));
using bf16 = __hip_bfloat16;
typedef unsigned short ushort_t;
typedef unsigned int   uint_t;

__device__ __forceinline__ float sigmoidf_(float x) { return 1.f / (1.f + __expf(-x)); }
__device__ __forceinline__ float bf2f(ushort_t u) { return __uint_as_float((uint_t)u << 16); }
__device__ __forceinline__ ushort_t f2bfu(float f) {
    bf16 h = __float2bfloat16(f);
    return *(ushort_t*)&h;
}
__device__ __forceinline__ void bf8_to_f(const ushort_t* __restrict__ p, float* __restrict__ f) {
    uint4 u = *(const uint4*)p;
    f[0] = __uint_as_float((u.x & 0xFFFFu) << 16);
    f[1] = __uint_as_float(u.x & 0xFFFF0000u);
    f[2] = __uint_as_float((u.y & 0xFFFFu) << 16);
    f[3] = __uint_as_float(u.y & 0xFFFF0000u);
    f[4] = __uint_as_float((u.z & 0xFFFFu) << 16);
    f[5] = __uint_as_float(u.z & 0xFFFF0000u);
    f[6] = __uint_as_float((u.w & 0xFFFFu) << 16);
    f[7] = __uint_as_float(u.w & 0xFFFF0000u);
}
__device__ __forceinline__ uint4 f8_to_bf(const float* __restrict__ f) {
    union { ushort_t s[8]; uint4 u; } r;
#pragma unroll
    for (int i = 0; i < 8; i++) r.s[i] = f2bfu(f[i]);
    return r.u;
}

// ---------------------------------------------------------------- GEMM (bf16 MFMA), fp32 inputs
// MODE 0: A = x fp32 (M x K), W = W_in fp32 (K x N, transposed in LDS).
//         Epilogue splits: z -> zbuf bf16, xBC-x -> xpx bf16, xBC-BC -> xpbc bf16,
//         dt -> softplus fused -> dtv/dalog fp32.
// MODE 1: A = yn bf16, W = W_out fp32 (K x N), out fp32 (harness output dtype).
template<int MODE>
__global__ __launch_bounds__(256, 2)
void gemm_k(const float* __restrict__ Af, const ushort_t* __restrict__ Ab,
            const float* __restrict__ W,
            ushort_t* __restrict__ zbuf, ushort_t* __restrict__ xpx,
            ushort_t* __restrict__ xpbc, float* __restrict__ dtv,
            float* __restrict__ dalog, const float* __restrict__ dt_b,
            const float* __restrict__ A_log, float* __restrict__ outf,
            int M, int N, int K)
{
    constexpr int SA = 72;
    __shared__ __align__(16) ushort_t As[128 * SA];
    __shared__ __align__(16) ushort_t Bs[128 * SA];

    const int tid  = threadIdx.x;
    const int wave = tid >> 6, lane = tid & 63;
    const int quad = lane >> 4, l16 = lane & 15;
    const int wm = (wave >> 1) * 64, wn = (wave & 1) * 64;
    const int m0 = blockIdx.y * 128, n0 = blockIdx.x * 128;

    const int srow = tid >> 1, scol = (tid & 1) * 32;  // A stage: 2 thr/row, 32 k each
    const int bkk  = tid & 63, bng  = tid >> 6;        // B stage: k-row, 32-n group
    const bool bfull = (n0 + 128 <= N);

    f32x4 acc[4][4];
#pragma unroll
    for (int i = 0; i < 4; i++)
#pragma unroll
        for (int j = 0; j < 4; j++) acc[i][j] = (f32x4){0.f, 0.f, 0.f, 0.f};

    for (int k0 = 0; k0 < K; k0 += 64) {
        // ---- load A (32 elems/thread) ----
        float aval[32];
        if (MODE == 0) {
            const float4* ap = (const float4*)(Af + (size_t)(m0 + srow) * K + k0 + scol);
#pragma unroll
            for (int j = 0; j < 8; j++) *(float4*)(aval + j * 4) = ap[j];
        } else {
            const ushort_t* ap = Ab + (size_t)(m0 + srow) * K + k0 + scol;
#pragma unroll
            for (int j = 0; j < 4; j++) bf8_to_f(ap + j * 8, aval + j * 8);
        }
        // ---- load B (32 elems/thread, row k0+bkk, cols n0+bng*32..+31) ----
        float bval[32];
        if (bfull) {
            const float4* bp = (const float4*)(W + (size_t)(k0 + bkk) * N + n0 + bng * 32);
#pragma unroll
            for (int j = 0; j < 8; j++) *(float4*)(bval + j * 4) = bp[j];
        } else {
            const float* bp = W + (size_t)(k0 + bkk) * N;
#pragma unroll
            for (int i = 0; i < 32; i++) {
                int ncol = n0 + bng * 32 + i;
                bval[i] = (ncol < N) ? bp[ncol] : 0.f;
            }
        }
        __syncthreads();
        // ---- store A (contiguous) ----
        {
            ushort_t* asw = &As[srow * SA + scol];
#pragma unroll
            for (int j = 0; j < 4; j++) *(uint4*)(asw + j * 8) = f8_to_bf(aval + j * 8);
        }
        // ---- store B transposed: Bs[n][k] ----
#pragma unroll
        for (int i = 0; i < 32; i++) Bs[(bng * 32 + i) * SA + bkk] = f2bfu(bval[i]);
        __syncthreads();
        // ---- MFMA ----
#pragma unroll
        for (int kk = 0; kk < 64; kk += 32) {
            bf16x8 af[4], bfr[4];
#pragma unroll
            for (int i = 0; i < 4; i++)
                af[i] = *(const bf16x8*)(&As[(wm + i * 16 + l16) * SA + kk + quad * 8]);
#pragma unroll
            for (int j = 0; j < 4; j++)
                bfr[j] = *(const bf16x8*)(&Bs[(wn + j * 16 + l16) * SA + kk + quad * 8]);
#pragma unroll
            for (int i = 0; i < 4; i++)
#pragma unroll
                for (int j = 0; j < 4; j++)
                    acc[i][j] = __builtin_amdgcn_mfma_f32_16x16x32_bf16(af[i], bfr[j], acc[i][j], 0, 0, 0);
        }
    }
    // ---- epilogue: C/D layout col=lane&15, row=quad*4+reg (m89/m91 verified) ----
#pragma unroll
    for (int i = 0; i < 4; i++) {
#pragma unroll
        for (int j = 0; j < 4; j++) {
            int col = n0 + wn + j * 16 + l16;
            int rowb = m0 + wm + i * 16 + quad * 4;
#pragma unroll
            for (int r = 0; r < 4; r++) {
                float v = acc[i][j][r];
                size_t g = (size_t)(rowb + r);
                if (MODE == 1) {
                    outf[g * N + col] = v;                       // fp32 output
                } else {
                    if (n0 < 1024)        zbuf[g * 1024 + col] = f2bfu(v);
                    else if (n0 < 2048)   xpx [g * 1024 + (col - 1024)] = f2bfu(v);
                    else if (n0 == 2048)  xpbc[g * 128  + (col - 2048)] = f2bfu(v);
                    else if (col < N) {
                        int hh = col - 2176;
                        float raw = v + dt_b[hh];
                        float sp  = (raw > 20.f) ? raw : log1pf(__expf(raw));
                        dtv  [g * NHEADS + hh] = sp;
                        dalog[g * NHEADS + hh] = -__expf(A_log[hh]) * sp;
                    }
                }
            }
        }
    }
}

// ---------------------------------------------------------------- fused sequential SSM scan
// One block per (h,b). Sequential over 64 chunks; state s[n][p] lives in LDS fp32.
// Staging applies the causal depthwise conv (taps from global pre-conv rows) + SiLU.
// Gate with silu(z) and write y IN PLACE over zbuf.
__global__ __launch_bounds__(256)
void ssm_scan_k(const ushort_t* __restrict__ xpx, const ushort_t* __restrict__ xpbc,
                ushort_t* zio,
                const float* __restrict__ dtv, const float* __restrict__ dalog,
                const float* __restrict__ cw, const float* __restrict__ cb,
                const float* __restrict__ Dp)
{
    const int h = blockIdx.x, b = blockIdx.y;
    __shared__ float sL[64 * 64];                     // state s[n][p]
    __shared__ __align__(16) ushort_t xsL[64 * 72];   // x (conv+silu), bf16
    __shared__ __align__(16) ushort_t BL_[64 * 72];   // B (conv+silu), bf16
    __shared__ float CL[64 * 65];                     // C -> att -> ybuf
    __shared__ float cum[64], wdt[64], wcL[64];
    __shared__ float decS;
    const int tid = threadIdx.x;
    const int ts = tid >> 2, q4 = (tid & 3) * 16;     // staging / state-update identity
    const int tL = tid & 63, grp = tid >> 6, p0 = grp * 16; // compute identity
    const float Dh = Dp[h];
    for (int i = tid; i < 4096; i += 256) sL[i] = 0.f;
    __syncthreads();

    for (int c = 0; c < NCHUNK; c++) {
        const int l = c * QCH + ts;
        const size_t grow = (size_t)b * SEQ + l;
        // ---- stage x-head slice with conv+silu ----
        {
            const int ch0 = h * HEADDIM + q4;
            float a16[16];
#pragma unroll
            for (int i = 0; i < 16; i++) a16[i] = cb[ch0 + i];
#pragma unroll
            for (int j = 0; j < 4; j++) {
                int ll = l - 3 + j;
                if (ll >= 0) {
                    float xv[16];
                    const ushort_t* rp = xpx + ((size_t)b * SEQ + ll) * 1024 + ch0;
                    bf8_to_f(rp, xv); bf8_to_f(rp + 8, xv + 8);
#pragma unroll
                    for (int i = 0; i < 16; i++) a16[i] += cw[(ch0 + i) * 4 + j] * xv[i];
                }
            }
#pragma unroll
            for (int i = 0; i < 16; i++) { float v = a16[i]; a16[i] = v * sigmoidf_(v); }
            *(uint4*)&xsL[ts * 72 + q4]     = f8_to_bf(a16);
            *(uint4*)&xsL[ts * 72 + q4 + 8] = f8_to_bf(a16 + 8);
        }
        // ---- stage B and C with conv+silu ----
        {
            float b16[16], c16[16];
#pragma unroll
            for (int i = 0; i < 16; i++) { b16[i] = cb[1024 + q4 + i]; c16[i] = cb[1088 + q4 + i]; }
#pragma unroll
            for (int j = 0; j < 4; j++) {
                int ll = l - 3 + j;
                if (ll >= 0) {
                    const ushort_t* rp = xpbc + ((size_t)b * SEQ + ll) * 128;
                    float bv[16], cv[16];
                    bf8_to_f(rp + q4, bv);      bf8_to_f(rp + q4 + 8, bv + 8);
                    bf8_to_f(rp + 64 + q4, cv); bf8_to_f(rp + 64 + q4 + 8, cv + 8);
#pragma unroll
                    for (int i = 0; i < 16; i++) {
                        b16[i] += cw[(1024 + q4 + i) * 4 + j] * bv[i];
                        c16[i] += cw[(1088 + q4 + i) * 4 + j] * cv[i];
                    }
                }
            }
#pragma unroll
            for (int i = 0; i < 16; i++) {
                float v = b16[i]; b16[i] = v * sigmoidf_(v);
                float u = c16[i]; c16[i] = u * sigmoidf_(u);
            }
            *(uint4*)&BL_[ts * 72 + q4]     = f8_to_bf(b16);
            *(uint4*)&BL_[ts * 72 + q4 + 8] = f8_to_bf(b16 + 8);
#pragma unroll
            for (int i = 0; i < 16; i++) CL[ts * 65 + q4 + i] = c16[i];
        }
        // ---- cumsum of dalog (wave 0) ----
        if (tid < 64) {
            size_t gl = ((size_t)b * SEQ + c * QCH + tid) * NHEADS + h;
            float v = dalog[gl];
#pragma unroll
            for (int off = 1; off < 64; off <<= 1) {
                float u = __shfl_up(v, off, 64);
                if (tid >= off) v += u;
            }
            float tot = __shfl(v, 63, 64);
            float dv  = dtv[gl];
            cum[tid] = v; wdt[tid] = dv;
            wcL[tid] = __expf(tot - v) * dv;
            if (tid == 63) decS = __expf(tot);
        }
        __syncthreads();
        // ---- C row into regs ----
        float cregs[64];
#pragma unroll
        for (int n = 0; n < 64; n++) cregs[n] = CL[tL * 65 + n];
        const float myc = cum[tL];
        __syncthreads();
        // ---- att[t][s] for this group's 16 s-columns ----
#pragma unroll
        for (int sj = 0; sj < 16; sj++) {
            const int s = p0 + sj;
            float a = 0.f;
            if (s <= tL) {
                float d = 0.f;
#pragma unroll
                for (int n4 = 0; n4 < 16; n4++) {
                    uint2 u = *(const uint2*)&BL_[s * 72 + n4 * 4];
                    d += cregs[n4 * 4 + 0] * __uint_as_float((u.x & 0xFFFFu) << 16)
                       + cregs[n4 * 4 + 1] * __uint_as_float(u.x & 0xFFFF0000u)
                       + cregs[n4 * 4 + 2] * __uint_as_float((u.y & 0xFFFFu) << 16)
                       + cregs[n4 * 4 + 3] * __uint_as_float(u.y & 0xFFFF0000u);
                }
                a = d * __expf(myc - cum[s]) * wdt[s];
            }
            CL[tL * 65 + s] = a;
        }
        __syncthreads();
        // ---- intra + inter + D into acc; local state into loc ----
        float acc[16];
#pragma unroll
        for (int j = 0; j < 16; j++) acc[j] = 0.f;
        for (int s = 0; s < 64; s++) {
            float a = CL[tL * 65 + s];
            float xv[16];
            bf8_to_f(&xsL[s * 72 + p0], xv); bf8_to_f(&xsL[s * 72 + p0 + 8], xv + 8);
#pragma unroll
            for (int j = 0; j < 16; j++) acc[j] += a * xv[j];
        }
        {
            float inter[16];
#pragma unroll
            for (int j = 0; j < 16; j++) inter[j] = 0.f;
#pragma unroll
            for (int n = 0; n < 64; n++) {
                float cn = cregs[n];
#pragma unroll
                for (int j4 = 0; j4 < 4; j4++) {
                    float4 sv = *(const float4*)&sL[n * 64 + p0 + j4 * 4];
                    inter[j4 * 4 + 0] += cn * sv.x; inter[j4 * 4 + 1] += cn * sv.y;
                    inter[j4 * 4 + 2] += cn * sv.z; inter[j4 * 4 + 3] += cn * sv.w;
                }
            }
            const float et = __expf(myc);
#pragma unroll
            for (int j = 0; j < 16; j++) acc[j] += et * inter[j];
        }
        {
            float xv[16];
            bf8_to_f(&xsL[tL * 72 + p0], xv); bf8_to_f(&xsL[tL * 72 + p0 + 8], xv + 8);
#pragma unroll
            for (int j = 0; j < 16; j++) acc[j] += Dh * xv[j];
        }
        float loc[16];
#pragma unroll
        for (int j = 0; j < 16; j++) loc[j] = 0.f;
        for (int t = 0; t < 64; t++) {
            float wb = wcL[t] * bf2f(BL_[t * 72 + ts]);   // ts = n index here
            float xv[16];
            bf8_to_f(&xsL[t * 72 + q4], xv); bf8_to_f(&xsL[t * 72 + q4 + 8], xv + 8);
#pragma unroll
            for (int j = 0; j < 16; j++) loc[j] += wb * xv[j];
        }
        __syncthreads();   // all sL / CL(att) reads done
        // ---- state update + ybuf ----
        {
            const float dec = decS;
#pragma unroll
            for (int j = 0; j < 16; j++) {
                float* sp = &sL[ts * 64 + q4 + j];
                *sp = dec * (*sp) + loc[j];
            }
#pragma unroll
            for (int j = 0; j < 16; j++) CL[tL * 65 + p0 + j] = acc[j];
        }
        __syncthreads();
        // ---- gate with silu(z), store in place ----
        {
            ushort_t* zrow = zio + grow * DINNER + h * HEADDIM + q4;
            float zv[16], o[16];
            bf8_to_f(zrow, zv); bf8_to_f(zrow + 8, zv + 8);
#pragma unroll
            for (int j = 0; j < 16; j++) {
                float z = zv[j];
                o[j] = CL[ts * 65 + q4 + j] * z * sigmoidf_(z);
            }
            *(uint4*)(zrow)     = f8_to_bf(o);
            *(uint4*)(zrow + 8) = f8_to_bf(o + 8);
        }
        __syncthreads();   // protect xsL/BL_/CL/sL before next chunk restage
    }
}

// ---------------------------------------------------------------- RMSNorm (in place, bf16)
__global__ void rmsnorm_k(ushort_t* yio, const float* __restrict__ nw)
{
    const int row = blockIdx.x, tid = threadIdx.x;
    uint2 u = *(const uint2*)(yio + (size_t)row * DINNER + tid * 4);
    float v0 = __uint_as_float((u.x & 0xFFFFu) << 16);
    float v1 = __uint_as_float(u.x & 0xFFFF0000u);
    float v2 = __uint_as_float((u.y & 0xFFFFu) << 16);
    float v3 = __uint_as_float(u.y & 0xFFFF0000u);
    float ss = v0 * v0 + v1 * v1 + v2 * v2 + v3 * v3;
#pragma unroll
    for (int off = 32; off >= 1; off >>= 1) ss += __shfl_xor(ss, off, 64);
    __shared__ float part[4];
    const int wave = tid >> 6;
    if ((tid & 63) == 0) part[wave] = ss;
    __syncthreads();
    float tot = part[0] + part[1] + part[2] + part[3];
    float scale = rsqrtf(tot * (1.f / DINNER) + 1e-5f);
    uint2 o;
    o.x = (uint_t)f2bfu(v0 * scale * nw[tid * 4 + 0]) | ((uint_t)f2bfu(v1 * scale * nw[tid * 4 + 1]) << 16);
    o.y = (uint_t)f2bfu(v2 * scale * nw[tid * 4 + 2]) | ((uint_t)f2bfu(v3 * scale * nw[tid * 4 + 3]) << 16);
    *(uint2*)(yio + (size_t)row * DINNER + tid * 4) = o;
}

// ---------------------------------------------------------------- launch
extern "C" void kernel_launch(void* const* d_in, const int* in_sizes, int n_in,
                              void* d_out, int out_size, void* d_ws, size_t ws_size,
                              hipStream_t stream)
{
    const float* x      = (const float*)d_in[0];   // (2,4096,512) fp32
    const float* W_in   = (const float*)d_in[1];   // (512,2192)  fp32
    const float* conv_w = (const float*)d_in[2];   // (1152,1,4)  fp32
    const float* conv_b = (const float*)d_in[3];   // (1152,)     fp32
    const float* dt_b   = (const float*)d_in[4];   // (16,)       fp32
    const float* A_log  = (const float*)d_in[5];   // (16,)       fp32
    const float* Dp     = (const float*)d_in[6];   // (16,)       fp32
    const float* nw     = (const float*)d_in[7];   // (1024,)     fp32
    const float* W_out  = (const float*)d_in[8];   // (1024,512)  fp32
    float* out = (float*)d_out;                    // (2,4096,512) fp32  <-- fixed

    // ---- workspace: 32 MiB high-water ----
    char* w = (char*)d_ws;
    ushort_t* zbuf = (ushort_t*)(w);               // [0,16M): z -> y -> yn (in place)
    ushort_t* xpx  = (ushort_t*)(w + 16777216);    // [16M,32M): pre-conv xBC x-part
    // ---- d_out (16 MiB fp32) doubles as scratch until GEMM2 overwrites it ----
    char* dscr = (char*)d_out;
    ushort_t* xpbc  = (ushort_t*)(dscr);           // [0, 2M): pre-conv B|C (128 cols)
    float*    dtv   = (float*)(dscr + 2097152);    // [2M, 2.5M)
    float*    dalog = (float*)(dscr + 2621440);    // [2.5M, 3M)

    gemm_k<0><<<dim3(18, MROWS / 128), 256, 0, stream>>>(
        x, nullptr, W_in, zbuf, xpx, xpbc, dtv, dalog, dt_b, A_log, nullptr,
        MROWS, NPROJ, DMODEL);
    ssm_scan_k<<<dim3(NHEADS, BATCH), 256, 0, stream>>>(
        xpx, xpbc, zbuf, dtv, dalog, conv_w, conv_b, Dp);
    rmsnorm_k<<<MROWS, 256, 0, stream>>>(zbuf, nw);
    gemm_k<1><<<dim3(4, MROWS / 128), 256, 0, stream>>>(
        nullptr, zbuf, W_out, nullptr, nullptr, nullptr, nullptr, nullptr,
        nullptr, nullptr, out, MROWS, DMODEL, DINNER);
}

// Round 6
// 390.192 us; speedup vs baseline: 20.1003x; 20.1003x over previous
//
#include <hip/hip_runtime.h>
#include <hip/hip_bf16.h>

#define BATCH   2
#define SEQ     4096
#define DMODEL  512
#define DINNER  1024
#define DSTATE  64
#define NHEADS  16
#define HEADDIM 64
#define CONVDIM 1152
#define NPROJ   2192
#define MROWS   (BATCH*SEQ)   // 8192
#define QCH     64
#define NCHUNK  (SEQ/QCH)     // 64 chunks per batch

typedef short bf16x8 __attribute__((ext_vector_type(8)));
typedef float f32x4  __attribute__((ext_vector_type(4)));
using bf16 = __hip_bfloat16;
typedef unsigned short ushort_t;
typedef unsigned int   uint_t;

__device__ __forceinline__ float sigmoidf_(float x) { return 1.f / (1.f + __expf(-x)); }
__device__ __forceinline__ float bf2f(ushort_t u) { return __uint_as_float((uint_t)u << 16); }
__device__ __forceinline__ ushort_t f2bfu(float f) {
    bf16 h = __float2bfloat16(f);
    return *(ushort_t*)&h;
}
__device__ __forceinline__ void bf8_to_f(const ushort_t* __restrict__ p, float* __restrict__ f) {
    uint4 u = *(const uint4*)p;
    f[0] = __uint_as_float((u.x & 0xFFFFu) << 16);
    f[1] = __uint_as_float(u.x & 0xFFFF0000u);
    f[2] = __uint_as_float((u.y & 0xFFFFu) << 16);
    f[3] = __uint_as_float(u.y & 0xFFFF0000u);
    f[4] = __uint_as_float((u.z & 0xFFFFu) << 16);
    f[5] = __uint_as_float(u.z & 0xFFFF0000u);
    f[6] = __uint_as_float((u.w & 0xFFFFu) << 16);
    f[7] = __uint_as_float(u.w & 0xFFFF0000u);
}
__device__ __forceinline__ uint4 f8_to_bf(const float* __restrict__ f) {
    union { ushort_t s[8]; uint4 u; } r;
#pragma unroll
    for (int i = 0; i < 8; i++) r.s[i] = f2bfu(f[i]);
    return r.u;
}

// ---------------------------------------------------------------- GEMM (bf16 MFMA), unchanged from R5 (proven)
template<int MODE>
__global__ __launch_bounds__(256, 2)
void gemm_k(const float* __restrict__ Af, const ushort_t* __restrict__ Ab,
            const float* __restrict__ W,
            ushort_t* __restrict__ zbuf, ushort_t* __restrict__ xpx,
            ushort_t* __restrict__ xpbc, float* __restrict__ dtv,
            float* __restrict__ dalog, const float* __restrict__ dt_b,
            const float* __restrict__ A_log, float* __restrict__ outf,
            int M, int N, int K)
{
    constexpr int SA = 72;
    __shared__ __align__(16) ushort_t As[128 * SA];
    __shared__ __align__(16) ushort_t Bs[128 * SA];

    const int tid  = threadIdx.x;
    const int wave = tid >> 6, lane = tid & 63;
    const int quad = lane >> 4, l16 = lane & 15;
    const int wm = (wave >> 1) * 64, wn = (wave & 1) * 64;
    const int m0 = blockIdx.y * 128, n0 = blockIdx.x * 128;

    const int srow = tid >> 1, scol = (tid & 1) * 32;
    const int bkk  = tid & 63, bng  = tid >> 6;
    const bool bfull = (n0 + 128 <= N);

    f32x4 acc[4][4];
#pragma unroll
    for (int i = 0; i < 4; i++)
#pragma unroll
        for (int j = 0; j < 4; j++) acc[i][j] = (f32x4){0.f, 0.f, 0.f, 0.f};

    for (int k0 = 0; k0 < K; k0 += 64) {
        float aval[32];
        if (MODE == 0) {
            const float4* ap = (const float4*)(Af + (size_t)(m0 + srow) * K + k0 + scol);
#pragma unroll
            for (int j = 0; j < 8; j++) *(float4*)(aval + j * 4) = ap[j];
        } else {
            const ushort_t* ap = Ab + (size_t)(m0 + srow) * K + k0 + scol;
#pragma unroll
            for (int j = 0; j < 4; j++) bf8_to_f(ap + j * 8, aval + j * 8);
        }
        float bval[32];
        if (bfull) {
            const float4* bp = (const float4*)(W + (size_t)(k0 + bkk) * N + n0 + bng * 32);
#pragma unroll
            for (int j = 0; j < 8; j++) *(float4*)(bval + j * 4) = bp[j];
        } else {
            const float* bp = W + (size_t)(k0 + bkk) * N;
#pragma unroll
            for (int i = 0; i < 32; i++) {
                int ncol = n0 + bng * 32 + i;
                bval[i] = (ncol < N) ? bp[ncol] : 0.f;
            }
        }
        __syncthreads();
        {
            ushort_t* asw = &As[srow * SA + scol];
#pragma unroll
            for (int j = 0; j < 4; j++) *(uint4*)(asw + j * 8) = f8_to_bf(aval + j * 8);
        }
#pragma unroll
        for (int i = 0; i < 32; i++) Bs[(bng * 32 + i) * SA + bkk] = f2bfu(bval[i]);
        __syncthreads();
#pragma unroll
        for (int kk = 0; kk < 64; kk += 32) {
            bf16x8 af[4], bfr[4];
#pragma unroll
            for (int i = 0; i < 4; i++)
                af[i] = *(const bf16x8*)(&As[(wm + i * 16 + l16) * SA + kk + quad * 8]);
#pragma unroll
            for (int j = 0; j < 4; j++)
                bfr[j] = *(const bf16x8*)(&Bs[(wn + j * 16 + l16) * SA + kk + quad * 8]);
#pragma unroll
            for (int i = 0; i < 4; i++)
#pragma unroll
                for (int j = 0; j < 4; j++)
                    acc[i][j] = __builtin_amdgcn_mfma_f32_16x16x32_bf16(af[i], bfr[j], acc[i][j], 0, 0, 0);
        }
    }
#pragma unroll
    for (int i = 0; i < 4; i++) {
#pragma unroll
        for (int j = 0; j < 4; j++) {
            int col = n0 + wn + j * 16 + l16;
            int rowb = m0 + wm + i * 16 + quad * 4;
#pragma unroll
            for (int r = 0; r < 4; r++) {
                float v = acc[i][j][r];
                size_t g = (size_t)(rowb + r);
                if (MODE == 1) {
                    outf[g * N + col] = v;
                } else {
                    if (n0 < 1024)        zbuf[g * 1024 + col] = f2bfu(v);
                    else if (n0 < 2048)   xpx [g * 1024 + (col - 1024)] = f2bfu(v);
                    else if (n0 == 2048)  xpbc[g * 128  + (col - 2048)] = f2bfu(v);
                    else if (col < N) {
                        int hh = col - 2176;
                        float raw = v + dt_b[hh];
                        float sp  = (raw > 20.f) ? raw : log1pf(__expf(raw));
                        dtv  [g * NHEADS + hh] = sp;
                        dalog[g * NHEADS + hh] = -__expf(A_log[hh]) * sp;
                    }
                }
            }
        }
    }
}

// ---------------------------------------------------------------- per-chunk state outer product (parallel, conv fused)
// states[c][b][h][n][p] = sum_t exp(cum63-cum_t)*dt_t * B[t][n] * x[t][p]   (bf16 out)
__global__ __launch_bounds__(256, 2)
void chunk_state_k(const ushort_t* __restrict__ xpx, const ushort_t* __restrict__ xpbc,
                   const float* __restrict__ dtv, const float* __restrict__ dalog,
                   const float* __restrict__ cw, const float* __restrict__ cb,
                   ushort_t* __restrict__ states, float* __restrict__ cdecay)
{
    const int c = blockIdx.x, h = blockIdx.y, b = blockIdx.z;
    __shared__ __align__(16) float xsL[64 * 68];
    __shared__ __align__(16) float BL [64 * 68];
    __shared__ float wc[64];
    const int tid = threadIdx.x;
    const int ts = tid >> 2, q4 = (tid & 3) * 16;
    const int l = c * QCH + ts;
    // ---- stage x (conv+silu) ----
    {
        const int ch0 = h * HEADDIM + q4;
        float a16[16];
#pragma unroll
        for (int i = 0; i < 16; i++) a16[i] = cb[ch0 + i];
#pragma unroll
        for (int j = 0; j < 4; j++) {
            int ll = l - 3 + j;
            if (ll >= 0) {
                float xv[16];
                const ushort_t* rp = xpx + ((size_t)b * SEQ + ll) * 1024 + ch0;
                bf8_to_f(rp, xv); bf8_to_f(rp + 8, xv + 8);
#pragma unroll
                for (int i = 0; i < 16; i++) a16[i] += cw[(ch0 + i) * 4 + j] * xv[i];
            }
        }
#pragma unroll
        for (int i = 0; i < 16; i++) { float v = a16[i]; xsL[ts * 68 + q4 + i] = v * sigmoidf_(v); }
    }
    // ---- stage B (conv+silu) ----
    {
        float b16[16];
#pragma unroll
        for (int i = 0; i < 16; i++) b16[i] = cb[1024 + q4 + i];
#pragma unroll
        for (int j = 0; j < 4; j++) {
            int ll = l - 3 + j;
            if (ll >= 0) {
                float bv[16];
                const ushort_t* rp = xpbc + ((size_t)b * SEQ + ll) * 128;
                bf8_to_f(rp + q4, bv); bf8_to_f(rp + q4 + 8, bv + 8);
#pragma unroll
                for (int i = 0; i < 16; i++) b16[i] += cw[(1024 + q4 + i) * 4 + j] * bv[i];
            }
        }
#pragma unroll
        for (int i = 0; i < 16; i++) { float v = b16[i]; BL[ts * 68 + q4 + i] = v * sigmoidf_(v); }
    }
    // ---- cumsum of dalog (wave 0) ----
    if (tid < 64) {
        size_t gl = ((size_t)b * SEQ + c * QCH + tid) * NHEADS + h;
        float v = dalog[gl];
#pragma unroll
        for (int off = 1; off < 64; off <<= 1) {
            float u = __shfl_up(v, off, 64);
            if (tid >= off) v += u;
        }
        float tot = __shfl(v, 63, 64);
        wc[tid] = __expf(tot - v) * dtv[gl];
        if (tid == 63) cdecay[(c * BATCH + b) * NHEADS + h] = __expf(tot);
    }
    __syncthreads();
    // ---- outer product ----
    const int n = tid >> 2, p0 = (tid & 3) * 16;
    float acc[16];
#pragma unroll
    for (int j = 0; j < 16; j++) acc[j] = 0.f;
    for (int t = 0; t < 64; t++) {
        float wb = wc[t] * BL[t * 68 + n];
#pragma unroll
        for (int j4 = 0; j4 < 4; j4++) {
            float4 xv = *(const float4*)&xsL[t * 68 + p0 + j4 * 4];
            acc[j4 * 4 + 0] += wb * xv.x; acc[j4 * 4 + 1] += wb * xv.y;
            acc[j4 * 4 + 2] += wb * xv.z; acc[j4 * 4 + 3] += wb * xv.w;
        }
    }
    ushort_t* sp = states + ((size_t)(c * BATCH + b) * NHEADS + h) * (HEADDIM * DSTATE) + n * HEADDIM + p0;
    *(uint4*)(sp + 0) = f8_to_bf(acc + 0);
    *(uint4*)(sp + 8) = f8_to_bf(acc + 8);
}

// ---------------------------------------------------------------- sequential chunk combine (bf16 states, fp32 accum)
// On exit: slot c holds s_prev (state BEFORE chunk c).
__global__ void scan_combine_k(ushort_t* __restrict__ states, const float* __restrict__ cdecay)
{
    const int blk = blockIdx.x;           // 128 = 2*16*4
    const int quarter = blk & 3;
    const int h = (blk >> 2) & 15;
    const int b = blk >> 6;
    const int tid = threadIdx.x;
    __shared__ float dec[64];
    if (tid < 64) dec[tid] = cdecay[(tid * BATCH + b) * NHEADS + h];
    __syncthreads();
    const size_t cstride = (size_t)BATCH * NHEADS * HEADDIM * DSTATE;  // elements
    ushort_t* base = states + ((size_t)b * NHEADS + h) * (HEADDIM * DSTATE) + quarter * 1024 + tid * 4;
    float sx = 0.f, sy = 0.f, sz = 0.f, sw = 0.f;
    uint2 pre[4];
#pragma unroll
    for (int j = 0; j < 4; j++) pre[j] = *(const uint2*)(base + j * cstride);
    for (int c = 0; c < NCHUNK; c++) {
        uint2 Sc = pre[c & 3];
        if (c + 4 < NCHUNK) pre[c & 3] = *(const uint2*)(base + (size_t)(c + 4) * cstride);
        float d = dec[c];
        uint2 o;
        o.x = (uint_t)f2bfu(sx) | ((uint_t)f2bfu(sy) << 16);
        o.y = (uint_t)f2bfu(sz) | ((uint_t)f2bfu(sw) << 16);
        *(uint2*)(base + (size_t)c * cstride) = o;
        sx = d * sx + __uint_as_float((Sc.x & 0xFFFFu) << 16);
        sy = d * sy + __uint_as_float(Sc.x & 0xFFFF0000u);
        sz = d * sz + __uint_as_float((Sc.y & 0xFFFFu) << 16);
        sw = d * sw + __uint_as_float(Sc.y & 0xFFFF0000u);
    }
}

// ---------------------------------------------------------------- per-chunk y (parallel): att + inter + D + gate
__global__ __launch_bounds__(256, 2)
void chunk_y_k(const ushort_t* __restrict__ xpx, const ushort_t* __restrict__ xpbc,
               ushort_t* zio,
               const float* __restrict__ dtv, const float* __restrict__ dalog,
               const ushort_t* __restrict__ states, const float* __restrict__ cw,
               const float* __restrict__ cb, const float* __restrict__ Dp)
{
    const int c = blockIdx.x, h = blockIdx.y, b = blockIdx.z;
    __shared__ __align__(16) float BL [64 * 68];  // B -> s_prev
    __shared__ __align__(16) float CL [64 * 65];  // C -> att -> ybuf
    __shared__ __align__(16) float xsL[64 * 68];  // x
    __shared__ float cum[64], wdt[64];
    const int tid = threadIdx.x;
    const int ts = tid >> 2, q4 = (tid & 3) * 16;
    const int l = c * QCH + ts;
    const float Dh = Dp[h];
    // ---- stage x (conv+silu) ----
    {
        const int ch0 = h * HEADDIM + q4;
        float a16[16];
#pragma unroll
        for (int i = 0; i < 16; i++) a16[i] = cb[ch0 + i];
#pragma unroll
        for (int j = 0; j < 4; j++) {
            int ll = l - 3 + j;
            if (ll >= 0) {
                float xv[16];
                const ushort_t* rp = xpx + ((size_t)b * SEQ + ll) * 1024 + ch0;
                bf8_to_f(rp, xv); bf8_to_f(rp + 8, xv + 8);
#pragma unroll
                for (int i = 0; i < 16; i++) a16[i] += cw[(ch0 + i) * 4 + j] * xv[i];
            }
        }
#pragma unroll
        for (int i = 0; i < 16; i++) { float v = a16[i]; xsL[ts * 68 + q4 + i] = v * sigmoidf_(v); }
    }
    // ---- stage B and C (conv+silu) ----
    {
        float b16[16], c16[16];
#pragma unroll
        for (int i = 0; i < 16; i++) { b16[i] = cb[1024 + q4 + i]; c16[i] = cb[1088 + q4 + i]; }
#pragma unroll
        for (int j = 0; j < 4; j++) {
            int ll = l - 3 + j;
            if (ll >= 0) {
                const ushort_t* rp = xpbc + ((size_t)b * SEQ + ll) * 128;
                float bv[16], cv[16];
                bf8_to_f(rp + q4, bv);      bf8_to_f(rp + q4 + 8, bv + 8);
                bf8_to_f(rp + 64 + q4, cv); bf8_to_f(rp + 64 + q4 + 8, cv + 8);
#pragma unroll
                for (int i = 0; i < 16; i++) {
                    b16[i] += cw[(1024 + q4 + i) * 4 + j] * bv[i];
                    c16[i] += cw[(1088 + q4 + i) * 4 + j] * cv[i];
                }
            }
        }
#pragma unroll
        for (int i = 0; i < 16; i++) {
            float v = b16[i]; BL[ts * 68 + q4 + i] = v * sigmoidf_(v);
            float u = c16[i]; CL[ts * 65 + q4 + i] = u * sigmoidf_(u);
        }
    }
    // ---- cumsum (wave 0) ----
    if (tid < 64) {
        size_t gl = ((size_t)b * SEQ + c * QCH + tid) * NHEADS + h;
        float v = dalog[gl];
#pragma unroll
        for (int off = 1; off < 64; off <<= 1) {
            float u = __shfl_up(v, off, 64);
            if (tid >= off) v += u;
        }
        cum[tid] = v;
        wdt[tid] = dtv[gl];
    }
    __syncthreads();
    const int tL = tid & 63, grp = tid >> 6, p0 = grp * 16;
    float cregs[64];
#pragma unroll
    for (int n = 0; n < 64; n++) cregs[n] = CL[tL * 65 + n];
    const float myc = cum[tL];
    __syncthreads();
    // ---- att[t][s] for this group's 16 s-columns ----
#pragma unroll
    for (int sj = 0; sj < 16; sj++) {
        const int s = p0 + sj;
        float a = 0.f;
        if (s <= tL) {
            float d = 0.f;
#pragma unroll
            for (int n4 = 0; n4 < 16; n4++) {
                float4 bv = *(const float4*)&BL[s * 68 + n4 * 4];
                d += cregs[n4 * 4 + 0] * bv.x + cregs[n4 * 4 + 1] * bv.y
                   + cregs[n4 * 4 + 2] * bv.z + cregs[n4 * 4 + 3] * bv.w;
            }
            a = d * __expf(myc - cum[s]) * wdt[s];
        }
        CL[tL * 65 + s] = a;
    }
    __syncthreads();
    // ---- intra ----
    float acc[16];
#pragma unroll
    for (int j = 0; j < 16; j++) acc[j] = 0.f;
    for (int s = 0; s < 64; s++) {
        float a = CL[tL * 65 + s];
#pragma unroll
        for (int j4 = 0; j4 < 4; j4++) {
            float4 xv = *(const float4*)&xsL[s * 68 + p0 + j4 * 4];
            acc[j4 * 4 + 0] += a * xv.x; acc[j4 * 4 + 1] += a * xv.y;
            acc[j4 * 4 + 2] += a * xv.z; acc[j4 * 4 + 3] += a * xv.w;
        }
    }
    // ---- stage s_prev into BL (att readers of BL done at last sync) ----
    {
        const ushort_t* sp = states + ((size_t)(c * BATCH + b) * NHEADS + h) * (HEADDIM * DSTATE) + ts * HEADDIM + q4;
        bf8_to_f(sp,     &BL[ts * 68 + q4]);
        bf8_to_f(sp + 8, &BL[ts * 68 + q4 + 8]);
    }
    __syncthreads();
    // ---- inter + D ----
    {
        float inter[16];
#pragma unroll
        for (int j = 0; j < 16; j++) inter[j] = 0.f;
#pragma unroll
        for (int n = 0; n < 64; n++) {
            float cn = cregs[n];
#pragma unroll
            for (int j4 = 0; j4 < 4; j4++) {
                float4 sv = *(const float4*)&BL[n * 68 + p0 + j4 * 4];
                inter[j4 * 4 + 0] += cn * sv.x; inter[j4 * 4 + 1] += cn * sv.y;
                inter[j4 * 4 + 2] += cn * sv.z; inter[j4 * 4 + 3] += cn * sv.w;
            }
        }
        const float et = __expf(myc);
#pragma unroll
        for (int j = 0; j < 16; j++) acc[j] += et * inter[j];
    }
#pragma unroll
    for (int j4 = 0; j4 < 4; j4++) {
        float4 xv = *(const float4*)&xsL[tL * 68 + p0 + j4 * 4];
        acc[j4 * 4 + 0] += Dh * xv.x; acc[j4 * 4 + 1] += Dh * xv.y;
        acc[j4 * 4 + 2] += Dh * xv.z; acc[j4 * 4 + 3] += Dh * xv.w;
    }
#pragma unroll
    for (int j = 0; j < 16; j++) CL[tL * 65 + p0 + j] = acc[j];
    __syncthreads();
    // ---- gate with silu(z), store in place (bf16) ----
    {
        ushort_t* zrow = zio + ((size_t)b * SEQ + l) * DINNER + h * HEADDIM + q4;
        float zv[16], o[16];
        bf8_to_f(zrow, zv); bf8_to_f(zrow + 8, zv + 8);
#pragma unroll
        for (int j = 0; j < 16; j++) {
            float z = zv[j];
            o[j] = CL[ts * 65 + q4 + j] * z * sigmoidf_(z);
        }
        *(uint4*)(zrow)     = f8_to_bf(o);
        *(uint4*)(zrow + 8) = f8_to_bf(o + 8);
    }
}

// ---------------------------------------------------------------- RMSNorm (in place, bf16) — unchanged
__global__ void rmsnorm_k(ushort_t* yio, const float* __restrict__ nw)
{
    const int row = blockIdx.x, tid = threadIdx.x;
    uint2 u = *(const uint2*)(yio + (size_t)row * DINNER + tid * 4);
    float v0 = __uint_as_float((u.x & 0xFFFFu) << 16);
    float v1 = __uint_as_float(u.x & 0xFFFF0000u);
    float v2 = __uint_as_float((u.y & 0xFFFFu) << 16);
    float v3 = __uint_as_float(u.y & 0xFFFF0000u);
    float ss = v0 * v0 + v1 * v1 + v2 * v2 + v3 * v3;
#pragma unroll
    for (int off = 32; off >= 1; off >>= 1) ss += __shfl_xor(ss, off, 64);
    __shared__ float part[4];
    const int wave = tid >> 6;
    if ((tid & 63) == 0) part[wave] = ss;
    __syncthreads();
    float tot = part[0] + part[1] + part[2] + part[3];
    float scale = rsqrtf(tot * (1.f / DINNER) + 1e-5f);
    uint2 o;
    o.x = (uint_t)f2bfu(v0 * scale * nw[tid * 4 + 0]) | ((uint_t)f2bfu(v1 * scale * nw[tid * 4 + 1]) << 16);
    o.y = (uint_t)f2bfu(v2 * scale * nw[tid * 4 + 2]) | ((uint_t)f2bfu(v3 * scale * nw[tid * 4 + 3]) << 16);
    *(uint2*)(yio + (size_t)row * DINNER + tid * 4) = o;
}

// ---------------------------------------------------------------- launch
extern "C" void kernel_launch(void* const* d_in, const int* in_sizes, int n_in,
                              void* d_out, int out_size, void* d_ws, size_t ws_size,
                              hipStream_t stream)
{
    const float* x      = (const float*)d_in[0];
    const float* W_in   = (const float*)d_in[1];
    const float* conv_w = (const float*)d_in[2];
    const float* conv_b = (const float*)d_in[3];
    const float* dt_b   = (const float*)d_in[4];
    const float* A_log  = (const float*)d_in[5];
    const float* Dp     = (const float*)d_in[6];
    const float* nw     = (const float*)d_in[7];
    const float* W_out  = (const float*)d_in[8];
    float* out = (float*)d_out;                    // (2,4096,512) fp32

    // ---- workspace (48 MiB high-water) ----
    char* w = (char*)d_ws;
    ushort_t* zbuf   = (ushort_t*)(w);                 // [0,16M): z -> y -> yn (in place)
    ushort_t* xpx    = (ushort_t*)(w + 16777216);      // [16M,32M): pre-conv xBC x-part
    ushort_t* states = (ushort_t*)(w + 33554432);      // [32M,48M): chunk states bf16
    // ---- d_out (16 MiB fp32) doubles as scratch until GEMM2 overwrites it ----
    char* dscr = (char*)d_out;
    ushort_t* xpbc  = (ushort_t*)(dscr);               // [0, 2M): pre-conv B|C
    float*    dtv   = (float*)(dscr + 2097152);        // [2M, 2.5M)
    float*    dalog = (float*)(dscr + 2621440);        // [2.5M, 3M)
    float*    cdec  = (float*)(dscr + 3145728);        // [3M, 3M+8K)

    gemm_k<0><<<dim3(18, MROWS / 128), 256, 0, stream>>>(
        x, nullptr, W_in, zbuf, xpx, xpbc, dtv, dalog, dt_b, A_log, nullptr,
        MROWS, NPROJ, DMODEL);
    chunk_state_k<<<dim3(NCHUNK, NHEADS, BATCH), 256, 0, stream>>>(
        xpx, xpbc, dtv, dalog, conv_w, conv_b, states, cdec);
    scan_combine_k<<<BATCH * NHEADS * 4, 256, 0, stream>>>(states, cdec);
    chunk_y_k<<<dim3(NCHUNK, NHEADS, BATCH), 256, 0, stream>>>(
        xpx, xpbc, zbuf, dtv, dalog, states, conv_w, conv_b, Dp);
    rmsnorm_k<<<MROWS, 256, 0, stream>>>(zbuf, nw);
    gemm_k<1><<<dim3(4, MROWS / 128), 256, 0, stream>>>(
        nullptr, zbuf, W_out, nullptr, nullptr, nullptr, nullptr, nullptr,
        nullptr, nullptr, out, MROWS, DMODEL, DINNER);
}

// Round 7
// 339.693 us; speedup vs baseline: 23.0884x; 1.1487x over previous
//
#include <hip/hip_runtime.h>
#include <hip/hip_bf16.h>

#define BATCH   2
#define SEQ     4096
#define DMODEL  512
#define DINNER  1024
#define DSTATE  64
#define NHEADS  16
#define HEADDIM 64
#define CONVDIM 1152
#define NPROJ   2192
#define MROWS   (BATCH*SEQ)   // 8192
#define QCH     64
#define NCHUNK  (SEQ/QCH)     // 64 chunks per batch

typedef short bf16x8 __attribute__((ext_vector_type(8)));
typedef float f32x4  __attribute__((ext_vector_type(4)));
using bf16 = __hip_bfloat16;
typedef unsigned short ushort_t;
typedef unsigned int   uint_t;

__device__ __forceinline__ float sigmoidf_(float x) { return 1.f / (1.f + __expf(-x)); }
__device__ __forceinline__ float bf2f(ushort_t u) { return __uint_as_float((uint_t)u << 16); }
__device__ __forceinline__ ushort_t f2bfu(float f) {
    bf16 h = __float2bfloat16(f);
    return *(ushort_t*)&h;
}
__device__ __forceinline__ void bf8_to_f(const ushort_t* __restrict__ p, float* __restrict__ f) {
    uint4 u = *(const uint4*)p;
    f[0] = __uint_as_float((u.x & 0xFFFFu) << 16);
    f[1] = __uint_as_float(u.x & 0xFFFF0000u);
    f[2] = __uint_as_float((u.y & 0xFFFFu) << 16);
    f[3] = __uint_as_float(u.y & 0xFFFF0000u);
    f[4] = __uint_as_float((u.z & 0xFFFFu) << 16);
    f[5] = __uint_as_float(u.z & 0xFFFF0000u);
    f[6] = __uint_as_float((u.w & 0xFFFFu) << 16);
    f[7] = __uint_as_float(u.w & 0xFFFF0000u);
}
__device__ __forceinline__ uint4 f8_to_bf(const float* __restrict__ f) {
    union { ushort_t s[8]; uint4 u; } r;
#pragma unroll
    for (int i = 0; i < 8; i++) r.s[i] = f2bfu(f[i]);
    return r.u;
}

// ---------------------------------------------------------------- GEMM (bf16 MFMA), unchanged (proven)
template<int MODE>
__global__ __launch_bounds__(256, 2)
void gemm_k(const float* __restrict__ Af, const ushort_t* __restrict__ Ab,
            const float* __restrict__ W,
            ushort_t* __restrict__ zbuf, ushort_t* __restrict__ xpx,
            ushort_t* __restrict__ xpbc, float* __restrict__ dtv,
            float* __restrict__ dalog, const float* __restrict__ dt_b,
            const float* __restrict__ A_log, float* __restrict__ outf,
            int M, int N, int K)
{
    constexpr int SA = 72;
    __shared__ __align__(16) ushort_t As[128 * SA];
    __shared__ __align__(16) ushort_t Bs[128 * SA];

    const int tid  = threadIdx.x;
    const int wave = tid >> 6, lane = tid & 63;
    const int quad = lane >> 4, l16 = lane & 15;
    const int wm = (wave >> 1) * 64, wn = (wave & 1) * 64;
    const int m0 = blockIdx.y * 128, n0 = blockIdx.x * 128;

    const int srow = tid >> 1, scol = (tid & 1) * 32;
    const int bkk  = tid & 63, bng  = tid >> 6;
    const bool bfull = (n0 + 128 <= N);

    f32x4 acc[4][4];
#pragma unroll
    for (int i = 0; i < 4; i++)
#pragma unroll
        for (int j = 0; j < 4; j++) acc[i][j] = (f32x4){0.f, 0.f, 0.f, 0.f};

    for (int k0 = 0; k0 < K; k0 += 64) {
        float aval[32];
        if (MODE == 0) {
            const float4* ap = (const float4*)(Af + (size_t)(m0 + srow) * K + k0 + scol);
#pragma unroll
            for (int j = 0; j < 8; j++) *(float4*)(aval + j * 4) = ap[j];
        } else {
            const ushort_t* ap = Ab + (size_t)(m0 + srow) * K + k0 + scol;
#pragma unroll
            for (int j = 0; j < 4; j++) bf8_to_f(ap + j * 8, aval + j * 8);
        }
        float bval[32];
        if (bfull) {
            const float4* bp = (const float4*)(W + (size_t)(k0 + bkk) * N + n0 + bng * 32);
#pragma unroll
            for (int j = 0; j < 8; j++) *(float4*)(bval + j * 4) = bp[j];
        } else {
            const float* bp = W + (size_t)(k0 + bkk) * N;
#pragma unroll
            for (int i = 0; i < 32; i++) {
                int ncol = n0 + bng * 32 + i;
                bval[i] = (ncol < N) ? bp[ncol] : 0.f;
            }
        }
        __syncthreads();
        {
            ushort_t* asw = &As[srow * SA + scol];
#pragma unroll
            for (int j = 0; j < 4; j++) *(uint4*)(asw + j * 8) = f8_to_bf(aval + j * 8);
        }
#pragma unroll
        for (int i = 0; i < 32; i++) Bs[(bng * 32 + i) * SA + bkk] = f2bfu(bval[i]);
        __syncthreads();
#pragma unroll
        for (int kk = 0; kk < 64; kk += 32) {
            bf16x8 af[4], bfr[4];
#pragma unroll
            for (int i = 0; i < 4; i++)
                af[i] = *(const bf16x8*)(&As[(wm + i * 16 + l16) * SA + kk + quad * 8]);
#pragma unroll
            for (int j = 0; j < 4; j++)
                bfr[j] = *(const bf16x8*)(&Bs[(wn + j * 16 + l16) * SA + kk + quad * 8]);
#pragma unroll
            for (int i = 0; i < 4; i++)
#pragma unroll
                for (int j = 0; j < 4; j++)
                    acc[i][j] = __builtin_amdgcn_mfma_f32_16x16x32_bf16(af[i], bfr[j], acc[i][j], 0, 0, 0);
        }
    }
#pragma unroll
    for (int i = 0; i < 4; i++) {
#pragma unroll
        for (int j = 0; j < 4; j++) {
            int col = n0 + wn + j * 16 + l16;
            int rowb = m0 + wm + i * 16 + quad * 4;
#pragma unroll
            for (int r = 0; r < 4; r++) {
                float v = acc[i][j][r];
                size_t g = (size_t)(rowb + r);
                if (MODE == 1) {
                    outf[g * N + col] = v;
                } else {
                    if (n0 < 1024)        zbuf[g * 1024 + col] = f2bfu(v);
                    else if (n0 < 2048)   xpx [g * 1024 + (col - 1024)] = f2bfu(v);
                    else if (n0 == 2048)  xpbc[g * 128  + (col - 2048)] = f2bfu(v);
                    else if (col < N) {
                        int hh = col - 2176;
                        float raw = v + dt_b[hh];
                        float sp  = (raw > 20.f) ? raw : log1pf(__expf(raw));
                        dtv  [g * NHEADS + hh] = sp;
                        dalog[g * NHEADS + hh] = -__expf(A_log[hh]) * sp;
                    }
                }
            }
        }
    }
}

// ---------------------------------------------------------------- per-chunk state outer product (MFMA)
// statesT[c][b][h][p][n] = sum_t xs[t][p] * (wc_t * B[t][n])    (bf16 out, TRANSPOSED [p][n])
__global__ __launch_bounds__(256, 2)
void chunk_state_k(const ushort_t* __restrict__ xpx, const ushort_t* __restrict__ xpbc,
                   const float* __restrict__ dtv, const float* __restrict__ dalog,
                   const float* __restrict__ cw, const float* __restrict__ cb,
                   ushort_t* __restrict__ statesT, float* __restrict__ cdecay)
{
    const int c = blockIdx.x, h = blockIdx.y, b = blockIdx.z;
    __shared__ __align__(16) ushort_t xsT[64 * 72];   // [p][t]  t-contig
    __shared__ __align__(16) ushort_t BwT[64 * 72];   // [n][t]  t-contig, weighted by wc[t]
    __shared__ float wc[64];
    const int tid = threadIdx.x;
    const int ts = tid >> 2, q4 = (tid & 3) * 16;
    const int l = c * QCH + ts;
    // ---- cumsum of dalog first (wave 0) — staging needs wc ----
    if (tid < 64) {
        size_t gl = ((size_t)b * SEQ + c * QCH + tid) * NHEADS + h;
        float v = dalog[gl];
#pragma unroll
        for (int off = 1; off < 64; off <<= 1) {
            float u = __shfl_up(v, off, 64);
            if (tid >= off) v += u;
        }
        float tot = __shfl(v, 63, 64);
        wc[tid] = __expf(tot - v) * dtv[gl];
        if (tid == 63) cdecay[(c * BATCH + b) * NHEADS + h] = __expf(tot);
    }
    __syncthreads();
    // ---- stage x (conv+silu) transposed into xsT[p][t] ----
    {
        const int ch0 = h * HEADDIM + q4;
        float a16[16];
#pragma unroll
        for (int i = 0; i < 16; i++) a16[i] = cb[ch0 + i];
#pragma unroll
        for (int j = 0; j < 4; j++) {
            int ll = l - 3 + j;
            if (ll >= 0) {
                float xv[16];
                const ushort_t* rp = xpx + ((size_t)b * SEQ + ll) * 1024 + ch0;
                bf8_to_f(rp, xv); bf8_to_f(rp + 8, xv + 8);
#pragma unroll
                for (int i = 0; i < 16; i++) a16[i] += cw[(ch0 + i) * 4 + j] * xv[i];
            }
        }
#pragma unroll
        for (int i = 0; i < 16; i++) { float v = a16[i]; xsT[(q4 + i) * 72 + ts] = f2bfu(v * sigmoidf_(v)); }
    }
    // ---- stage B (conv+silu, weighted) transposed into BwT[n][t] ----
    {
        float b16[16];
#pragma unroll
        for (int i = 0; i < 16; i++) b16[i] = cb[1024 + q4 + i];
#pragma unroll
        for (int j = 0; j < 4; j++) {
            int ll = l - 3 + j;
            if (ll >= 0) {
                float bv[16];
                const ushort_t* rp = xpbc + ((size_t)b * SEQ + ll) * 128;
                bf8_to_f(rp + q4, bv); bf8_to_f(rp + q4 + 8, bv + 8);
#pragma unroll
                for (int i = 0; i < 16; i++) b16[i] += cw[(1024 + q4 + i) * 4 + j] * bv[i];
            }
        }
        const float wt = wc[ts];
#pragma unroll
        for (int i = 0; i < 16; i++) { float v = b16[i]; BwT[(q4 + i) * 72 + ts] = f2bfu(v * sigmoidf_(v) * wt); }
    }
    __syncthreads();
    // ---- MFMA: D[p][n] = sum_t xsT[p][t] * BwT[n][t] ; wave strip over p ----
    const int wave = tid >> 6, lane = tid & 63;
    const int quad = lane >> 4, l16 = lane & 15;
    f32x4 acc[4];
#pragma unroll
    for (int j = 0; j < 4; j++) acc[j] = (f32x4){0.f, 0.f, 0.f, 0.f};
#pragma unroll
    for (int kk = 0; kk < 64; kk += 32) {
        bf16x8 af = *(const bf16x8*)(&xsT[(wave * 16 + l16) * 72 + kk + quad * 8]);
#pragma unroll
        for (int j = 0; j < 4; j++) {
            bf16x8 bf_ = *(const bf16x8*)(&BwT[(j * 16 + l16) * 72 + kk + quad * 8]);
            acc[j] = __builtin_amdgcn_mfma_f32_16x16x32_bf16(af, bf_, acc[j], 0, 0, 0);
        }
    }
    ushort_t* base = statesT + ((size_t)(c * BATCH + b) * NHEADS + h) * (HEADDIM * DSTATE);
#pragma unroll
    for (int j = 0; j < 4; j++)
#pragma unroll
        for (int r = 0; r < 4; r++)
            base[(wave * 16 + quad * 4 + r) * 64 + j * 16 + l16] = f2bfu(acc[j][r]);
}

// ---------------------------------------------------------------- sequential chunk combine (elementwise; layout-agnostic)
__global__ void scan_combine_k(ushort_t* __restrict__ states, const float* __restrict__ cdecay)
{
    const int blk = blockIdx.x;           // 128 = 2*16*4
    const int quarter = blk & 3;
    const int h = (blk >> 2) & 15;
    const int b = blk >> 6;
    const int tid = threadIdx.x;
    __shared__ float dec[64];
    if (tid < 64) dec[tid] = cdecay[(tid * BATCH + b) * NHEADS + h];
    __syncthreads();
    const size_t cstride = (size_t)BATCH * NHEADS * HEADDIM * DSTATE;  // elements
    ushort_t* base = states + ((size_t)b * NHEADS + h) * (HEADDIM * DSTATE) + quarter * 1024 + tid * 4;
    float sx = 0.f, sy = 0.f, sz = 0.f, sw = 0.f;
    uint2 pre[4];
#pragma unroll
    for (int j = 0; j < 4; j++) pre[j] = *(const uint2*)(base + j * cstride);
    for (int c = 0; c < NCHUNK; c++) {
        uint2 Sc = pre[c & 3];
        if (c + 4 < NCHUNK) pre[c & 3] = *(const uint2*)(base + (size_t)(c + 4) * cstride);
        float d = dec[c];
        uint2 o;
        o.x = (uint_t)f2bfu(sx) | ((uint_t)f2bfu(sy) << 16);
        o.y = (uint_t)f2bfu(sz) | ((uint_t)f2bfu(sw) << 16);
        *(uint2*)(base + (size_t)c * cstride) = o;
        sx = d * sx + __uint_as_float((Sc.x & 0xFFFFu) << 16);
        sy = d * sy + __uint_as_float(Sc.x & 0xFFFF0000u);
        sz = d * sz + __uint_as_float((Sc.y & 0xFFFFu) << 16);
        sw = d * sw + __uint_as_float(Sc.y & 0xFFFF0000u);
    }
}

// ---------------------------------------------------------------- per-chunk y (MFMA): att + intra + inter + D + gate
__global__ __launch_bounds__(256, 2)
void chunk_y_k(const ushort_t* __restrict__ xpx, const ushort_t* __restrict__ xpbc,
               ushort_t* zio,
               const float* __restrict__ dtv, const float* __restrict__ dalog,
               const ushort_t* __restrict__ statesT, const float* __restrict__ cw,
               const float* __restrict__ cb, const float* __restrict__ Dp)
{
    const int c = blockIdx.x, h = blockIdx.y, b = blockIdx.z;
    __shared__ __align__(16) ushort_t CLb [64 * 72];  // C[t][n] n-contig
    __shared__ __align__(16) ushort_t BLb [64 * 72];  // B[s][n] n-contig -> ybuf[t][p]
    __shared__ __align__(16) ushort_t xsT [64 * 72];  // xs^T [p][t] t-contig
    __shared__ __align__(16) ushort_t attL[64 * 72];  // att[t][s] s-contig
    __shared__ float cum[64], wdt[64];
    const int tid = threadIdx.x;
    const int ts = tid >> 2, q4 = (tid & 3) * 16;
    const int l = c * QCH + ts;
    const float Dh = Dp[h];
    // ---- stage x (conv+silu) transposed ----
    {
        const int ch0 = h * HEADDIM + q4;
        float a16[16];
#pragma unroll
        for (int i = 0; i < 16; i++) a16[i] = cb[ch0 + i];
#pragma unroll
        for (int j = 0; j < 4; j++) {
            int ll = l - 3 + j;
            if (ll >= 0) {
                float xv[16];
                const ushort_t* rp = xpx + ((size_t)b * SEQ + ll) * 1024 + ch0;
                bf8_to_f(rp, xv); bf8_to_f(rp + 8, xv + 8);
#pragma unroll
                for (int i = 0; i < 16; i++) a16[i] += cw[(ch0 + i) * 4 + j] * xv[i];
            }
        }
#pragma unroll
        for (int i = 0; i < 16; i++) { float v = a16[i]; xsT[(q4 + i) * 72 + ts] = f2bfu(v * sigmoidf_(v)); }
    }
    // ---- stage B and C (conv+silu), row layout n-contig ----
    {
        float b16[16], c16[16];
#pragma unroll
        for (int i = 0; i < 16; i++) { b16[i] = cb[1024 + q4 + i]; c16[i] = cb[1088 + q4 + i]; }
#pragma unroll
        for (int j = 0; j < 4; j++) {
            int ll = l - 3 + j;
            if (ll >= 0) {
                const ushort_t* rp = xpbc + ((size_t)b * SEQ + ll) * 128;
                float bv[16], cv[16];
                bf8_to_f(rp + q4, bv);      bf8_to_f(rp + q4 + 8, bv + 8);
                bf8_to_f(rp + 64 + q4, cv); bf8_to_f(rp + 64 + q4 + 8, cv + 8);
#pragma unroll
                for (int i = 0; i < 16; i++) {
                    b16[i] += cw[(1024 + q4 + i) * 4 + j] * bv[i];
                    c16[i] += cw[(1088 + q4 + i) * 4 + j] * cv[i];
                }
            }
        }
        float bs[16], cs[16];
#pragma unroll
        for (int i = 0; i < 16; i++) {
            float v = b16[i]; bs[i] = v * sigmoidf_(v);
            float u = c16[i]; cs[i] = u * sigmoidf_(u);
        }
        *(uint4*)&BLb[ts * 72 + q4]     = f8_to_bf(bs);
        *(uint4*)&BLb[ts * 72 + q4 + 8] = f8_to_bf(bs + 8);
        *(uint4*)&CLb[ts * 72 + q4]     = f8_to_bf(cs);
        *(uint4*)&CLb[ts * 72 + q4 + 8] = f8_to_bf(cs + 8);
    }
    // ---- cumsum (wave 0) ----
    if (tid < 64) {
        size_t gl = ((size_t)b * SEQ + c * QCH + tid) * NHEADS + h;
        float v = dalog[gl];
#pragma unroll
        for (int off = 1; off < 64; off <<= 1) {
            float u = __shfl_up(v, off, 64);
            if (tid >= off) v += u;
        }
        cum[tid] = v;
        wdt[tid] = dtv[gl];
    }
    __syncthreads();
    const int wave = tid >> 6, lane = tid & 63;
    const int quad = lane >> 4, l16 = lane & 15;
    // ---- matmul1: S[t][s] = sum_n C[t][n]*B[s][n]; scale+mask -> attL bf16 ----
    {
        f32x4 sacc[4];
#pragma unroll
        for (int j = 0; j < 4; j++) sacc[j] = (f32x4){0.f, 0.f, 0.f, 0.f};
#pragma unroll
        for (int kk = 0; kk < 64; kk += 32) {
            bf16x8 af = *(const bf16x8*)(&CLb[(wave * 16 + l16) * 72 + kk + quad * 8]);
#pragma unroll
            for (int j = 0; j < 4; j++) {
                bf16x8 bf_ = *(const bf16x8*)(&BLb[(j * 16 + l16) * 72 + kk + quad * 8]);
                sacc[j] = __builtin_amdgcn_mfma_f32_16x16x32_bf16(af, bf_, sacc[j], 0, 0, 0);
            }
        }
#pragma unroll
        for (int r = 0; r < 4; r++) {
            const int t = wave * 16 + quad * 4 + r;
            const float ct = cum[t];
#pragma unroll
            for (int j = 0; j < 4; j++) {
                const int s = j * 16 + l16;
                float a = (s <= t) ? sacc[j][r] * __expf(ct - cum[s]) * wdt[s] : 0.f;
                attL[t * 72 + s] = f2bfu(a);
            }
        }
    }
    __syncthreads();
    // ---- matmul2: Y[t][p] = att·xs ; matmul3: I[t][p] = C·sprev (B-frags from global statesT) ----
    {
        f32x4 accY[4], accI[4];
#pragma unroll
        for (int j = 0; j < 4; j++) { accY[j] = (f32x4){0.f, 0.f, 0.f, 0.f}; accI[j] = (f32x4){0.f, 0.f, 0.f, 0.f}; }
        const ushort_t* spg = statesT + ((size_t)(c * BATCH + b) * NHEADS + h) * (HEADDIM * DSTATE);
#pragma unroll
        for (int kk = 0; kk < 64; kk += 32) {
            bf16x8 a2 = *(const bf16x8*)(&attL[(wave * 16 + l16) * 72 + kk + quad * 8]);
            bf16x8 a3 = *(const bf16x8*)(&CLb [(wave * 16 + l16) * 72 + kk + quad * 8]);
#pragma unroll
            for (int j = 0; j < 4; j++) {
                bf16x8 b2 = *(const bf16x8*)(&xsT[(j * 16 + l16) * 72 + kk + quad * 8]);
                accY[j] = __builtin_amdgcn_mfma_f32_16x16x32_bf16(a2, b2, accY[j], 0, 0, 0);
                bf16x8 b3 = *(const bf16x8*)(spg + (j * 16 + l16) * 64 + kk + quad * 8);
                accI[j] = __builtin_amdgcn_mfma_f32_16x16x32_bf16(a3, b3, accI[j], 0, 0, 0);
            }
        }
        // combine: y = accY + exp(cum_t)*accI + D*xs[t][p] ; store ybuf over BLb
#pragma unroll
        for (int r = 0; r < 4; r++) {
            const int t = wave * 16 + quad * 4 + r;
            const float et = __expf(cum[t]);
#pragma unroll
            for (int j = 0; j < 4; j++) {
                const int p = j * 16 + l16;
                float xv = bf2f(xsT[p * 72 + t]);
                float y = accY[j][r] + et * accI[j][r] + Dh * xv;
                BLb[t * 72 + p] = f2bfu(y);
            }
        }
    }
    __syncthreads();
    // ---- gate with silu(z), store in place (bf16) ----
    {
        ushort_t* zrow = zio + ((size_t)b * SEQ + l) * DINNER + h * HEADDIM + q4;
        float zv[16], yv[16], o[16];
        bf8_to_f(zrow, zv); bf8_to_f(zrow + 8, zv + 8);
        bf8_to_f(&BLb[ts * 72 + q4], yv); bf8_to_f(&BLb[ts * 72 + q4 + 8], yv + 8);
#pragma unroll
        for (int j = 0; j < 16; j++) {
            float z = zv[j];
            o[j] = yv[j] * z * sigmoidf_(z);
        }
        *(uint4*)(zrow)     = f8_to_bf(o);
        *(uint4*)(zrow + 8) = f8_to_bf(o + 8);
    }
}

// ---------------------------------------------------------------- RMSNorm (in place, bf16) — unchanged
__global__ void rmsnorm_k(ushort_t* yio, const float* __restrict__ nw)
{
    const int row = blockIdx.x, tid = threadIdx.x;
    uint2 u = *(const uint2*)(yio + (size_t)row * DINNER + tid * 4);
    float v0 = __uint_as_float((u.x & 0xFFFFu) << 16);
    float v1 = __uint_as_float(u.x & 0xFFFF0000u);
    float v2 = __uint_as_float((u.y & 0xFFFFu) << 16);
    float v3 = __uint_as_float(u.y & 0xFFFF0000u);
    float ss = v0 * v0 + v1 * v1 + v2 * v2 + v3 * v3;
#pragma unroll
    for (int off = 32; off >= 1; off >>= 1) ss += __shfl_xor(ss, off, 64);
    __shared__ float part[4];
    const int wave = tid >> 6;
    if ((tid & 63) == 0) part[wave] = ss;
    __syncthreads();
    float tot = part[0] + part[1] + part[2] + part[3];
    float scale = rsqrtf(tot * (1.f / DINNER) + 1e-5f);
    uint2 o;
    o.x = (uint_t)f2bfu(v0 * scale * nw[tid * 4 + 0]) | ((uint_t)f2bfu(v1 * scale * nw[tid * 4 + 1]) << 16);
    o.y = (uint_t)f2bfu(v2 * scale * nw[tid * 4 + 2]) | ((uint_t)f2bfu(v3 * scale * nw[tid * 4 + 3]) << 16);
    *(uint2*)(yio + (size_t)row * DINNER + tid * 4) = o;
}

// ---------------------------------------------------------------- launch
extern "C" void kernel_launch(void* const* d_in, const int* in_sizes, int n_in,
                              void* d_out, int out_size, void* d_ws, size_t ws_size,
                              hipStream_t stream)
{
    const float* x      = (const float*)d_in[0];
    const float* W_in   = (const float*)d_in[1];
    const float* conv_w = (const float*)d_in[2];
    const float* conv_b = (const float*)d_in[3];
    const float* dt_b   = (const float*)d_in[4];
    const float* A_log  = (const float*)d_in[5];
    const float* Dp     = (const float*)d_in[6];
    const float* nw     = (const float*)d_in[7];
    const float* W_out  = (const float*)d_in[8];
    float* out = (float*)d_out;                    // (2,4096,512) fp32

    // ---- workspace (48 MiB high-water) ----
    char* w = (char*)d_ws;
    ushort_t* zbuf    = (ushort_t*)(w);                 // [0,16M): z -> y -> yn (in place)
    ushort_t* xpx     = (ushort_t*)(w + 16777216);      // [16M,32M): pre-conv xBC x-part
    ushort_t* statesT = (ushort_t*)(w + 33554432);      // [32M,48M): chunk states bf16 [p][n]
    // ---- d_out (16 MiB fp32) doubles as scratch until GEMM2 overwrites it ----
    char* dscr = (char*)d_out;
    ushort_t* xpbc  = (ushort_t*)(dscr);                // [0, 2M): pre-conv B|C
    float*    dtv   = (float*)(dscr + 2097152);         // [2M, 2.5M)
    float*    dalog = (float*)(dscr + 2621440);         // [2.5M, 3M)
    float*    cdec  = (float*)(dscr + 3145728);         // [3M, 3M+8K)

    gemm_k<0><<<dim3(18, MROWS / 128), 256, 0, stream>>>(
        x, nullptr, W_in, zbuf, xpx, xpbc, dtv, dalog, dt_b, A_log, nullptr,
        MROWS, NPROJ, DMODEL);
    chunk_state_k<<<dim3(NCHUNK, NHEADS, BATCH), 256, 0, stream>>>(
        xpx, xpbc, dtv, dalog, conv_w, conv_b, statesT, cdec);
    scan_combine_k<<<BATCH * NHEADS * 4, 256, 0, stream>>>(statesT, cdec);
    chunk_y_k<<<dim3(NCHUNK, NHEADS, BATCH), 256, 0, stream>>>(
        xpx, xpbc, zbuf, dtv, dalog, statesT, conv_w, conv_b, Dp);
    rmsnorm_k<<<MROWS, 256, 0, stream>>>(zbuf, nw);
    gemm_k<1><<<dim3(4, MROWS / 128), 256, 0, stream>>>(
        nullptr, zbuf, W_out, nullptr, nullptr, nullptr, nullptr, nullptr,
        nullptr, nullptr, out, MROWS, DMODEL, DINNER);
}